// Round 8
// baseline (56.406 us; speedup 1.0000x reference)
//
#include <hip/hip_runtime.h>

// LengthRegulator: expand x[B,T,D] by integer durations into out[B,MAX_LEN,D],
// plus mel_len[B] = cumsum(duration)[:, -1].
// B=32, T=512, D=512, MAX_LEN=4096, durations in [0,10).
//
// R7: R6 (one wave per token, register-pure store burst) with ONE change:
// zero-fill region [mel, MAX_LEN) is now covered by CONTIGUOUS per-wave
// chunks (wave t writes slab [mel+t*chunk, mel+(t+1)*chunk)) instead of the
// 512-stride interleave (which made ~42% of write traffic isolated 2 KB
// rows at 1 MB stride -- bad DRAM page locality).

typedef float f32x4 __attribute__((ext_vector_type(4)));
typedef int   i32x4 __attribute__((ext_vector_type(4)));

#define B_      32
#define T_      512
#define D_      512
#define MAXLEN_ 4096
#define BPB_    128                      // blocks per batch (4 tokens/block)
#define NBLK_   (B_ * BPB_)              // 4096 blocks

__global__ void lr_fused_kernel(const float* __restrict__ x,
                                const int* __restrict__ dur,
                                float* __restrict__ out,
                                float* __restrict__ mel_out) {
    const int gid  = blockIdx.x;
    const int b    = gid >> 7;               // / BPB_
    const int blk  = gid & (BPB_ - 1);
    const int wid  = threadIdx.x >> 6;       // wave id 0..3
    const int lane = threadIdx.x & 63;
    const int t    = blk * 4 + wid;          // wave-uniform token

    // ---- issue the row load FIRST (independent of the scan) ----
    const f32x4* row = (const f32x4*)(x + ((size_t)b * T_ + t) * D_);
    const f32x4 va = row[lane];
    const f32x4 vb = row[lane + 64];

    // ---- wave-redundant inclusive scan of duration[b][:] in registers ----
    const i32x4* src = (const i32x4*)(dur + b * T_);
    i32x4 a = src[lane * 2];
    i32x4 c = src[lane * 2 + 1];
    int v0 = a.x,      v1 = v0 + a.y, v2 = v1 + a.z, v3 = v2 + a.w;
    int v4 = v3 + c.x, v5 = v4 + c.y, v6 = v5 + c.z, v7 = v6 + c.w;
    int s = v7;
    #pragma unroll
    for (int d = 1; d < 64; d <<= 1) {
        int u = __shfl_up(s, d, 64);
        if (lane >= d) s += u;
    }
    const int off = s - v7;                  // exclusive prefix of this lane
    v0 += off; v1 += off; v2 += off; v3 += off;
    v4 += off; v5 += off; v6 += off; v7 += off;
    // lane l holds cum[8l .. 8l+7]

    const int mel = __shfl(v7, 63, 64);

    // ---- hi = cum[t], lo = cum[t-1] (t wave-uniform) ----
    const int e = t & 7;
    int sel = v0;
    sel = (e == 1) ? v1 : sel;  sel = (e == 2) ? v2 : sel;
    sel = (e == 3) ? v3 : sel;  sel = (e == 4) ? v4 : sel;
    sel = (e == 5) ? v5 : sel;  sel = (e == 6) ? v6 : sel;
    sel = (e == 7) ? v7 : sel;
    int hi = __shfl(sel, t >> 3, 64);
    int lo = 0;
    if (t > 0) {
        const int e2 = (t - 1) & 7;
        int sl = v0;
        sl = (e2 == 1) ? v1 : sl;  sl = (e2 == 2) ? v2 : sl;
        sl = (e2 == 3) ? v3 : sl;  sl = (e2 == 4) ? v4 : sl;
        sl = (e2 == 5) ? v5 : sl;  sl = (e2 == 6) ? v6 : sl;
        sl = (e2 == 7) ? v7 : sl;
        lo = __shfl(sl, (t - 1) >> 3, 64);
    }
    hi = min(hi, MAXLEN_);                   // robustness clamp
    lo = min(lo, MAXLEN_);

    // ---- expand: write the row to frames [lo, hi) ----
    f32x4* dst = (f32x4*)(out + ((size_t)b * MAXLEN_ + lo) * D_);
    for (int i = 0; i < hi - lo; ++i) {
        __builtin_nontemporal_store(va, dst + i * 128 + lane);
        __builtin_nontemporal_store(vb, dst + i * 128 + lane + 64);
    }

    // ---- zero-fill: contiguous per-wave chunk of [mel, MAXLEN_) ----
    const int nz    = MAXLEN_ - mel;
    const int chunk = (nz + T_ - 1) >> 9;    // ceil(nz / 512)
    const int z0    = mel + t * chunk;
    const int z1    = min(z0 + chunk, MAXLEN_);
    const f32x4 z = {0.f, 0.f, 0.f, 0.f};
    for (int f = z0; f < z1; ++f) {
        f32x4* dz = (f32x4*)(out + ((size_t)b * MAXLEN_ + f) * D_);
        __builtin_nontemporal_store(z, dz + lane);
        __builtin_nontemporal_store(z, dz + lane + 64);
    }

    if (blk == 0 && threadIdx.x == 0) mel_out[b] = (float)mel;
}

extern "C" void kernel_launch(void* const* d_in, const int* in_sizes, int n_in,
                              void* d_out, int out_size, void* d_ws, size_t ws_size,
                              hipStream_t stream) {
    const float* x   = (const float*)d_in[0];
    const int*   dur = (const int*)d_in[1];
    // d_in[2] is max_len (=4096), compile-time constant here.

    float* out     = (float*)d_out;
    float* mel_out = out + (size_t)B_ * MAXLEN_ * D_;   // tail: 32 elements

    lr_fused_kernel<<<NBLK_, 256, 0, stream>>>(x, dur, out, mel_out);
}